// Round 3
// baseline (242.234 us; speedup 1.0000x reference)
//
#include <hip/hip_runtime.h>
#include <hip/hip_bf16.h>
#include <cstdint>

typedef __attribute__((ext_vector_type(4))) float f32x4;
typedef __attribute__((ext_vector_type(8))) short s16x8;

#define NB   32
#define NL   2048
#define NH   512
#define NM   (NB * NL)          // 65536 rows
#define SCALE 0.04419417382415922f  // 1/sqrt(512)
#define LDST 36                 // padded LDS row stride (ushorts): gcd(18 dwords,32 banks)=2 -> 2-way max (free)
#define BUFO (128 * LDST)       // ushorts per LDS buffer

__device__ __forceinline__ ushort f2bf(float f) {
    __hip_bfloat16 b = __float2bfloat16(f);   // compiler fuses pairs into v_cvt_pk_bf16_f32
    return *reinterpret_cast<ushort*>(&b);
}

// ---- convert W_ref (512x512 f32) to bf16 ----
__global__ __launch_bounds__(256) void k_convW(const float* __restrict__ W,
                                               ushort* __restrict__ Wb) {
    int i = blockIdx.x * 256 + threadIdx.x;        // 32768 threads, 8 f32 each
    const float4* s = (const float4*)W;
    float4 a = s[2 * i], c = s[2 * i + 1];
    union { ushort u[8]; int4 v; } p;
    p.u[0] = f2bf(a.x); p.u[1] = f2bf(a.y); p.u[2] = f2bf(a.z); p.u[3] = f2bf(a.w);
    p.u[4] = f2bf(c.x); p.u[5] = f2bf(c.y); p.u[6] = f2bf(c.z); p.u[7] = f2bf(c.w);
    ((int4*)Wb)[i] = p.v;
}

// ---- eq[b][o] = dot(query[b,:], W_q[o,:]) ----
__global__ __launch_bounds__(512) void k_eq(const float* __restrict__ query,
                                            const float* __restrict__ Wq,
                                            float* __restrict__ eq) {
    int b = blockIdx.x;
    int o = threadIdx.x;
    __shared__ float q[NH];
    q[o] = query[b * NH + o];
    __syncthreads();
    const float4* w = (const float4*)(Wq + (size_t)o * NH);
    float acc = 0.f;
#pragma unroll 4
    for (int i = 0; i < NH / 4; ++i) {
        float4 x = w[i];
        acc += q[4 * i] * x.x + q[4 * i + 1] * x.y + q[4 * i + 2] * x.z + q[4 * i + 3] * x.w;
    }
    eq[b * NH + o] = acc;
}

// ---- fused GEMM (ref @ W_ref^T) + tanh + v-dot partial ----
// grid 2048 blocks x 256 thr. Tile 128x128, K-step 32, 4 waves (2x2), 4x4 frags/wave.
// Canonical 2-phase: LDS double-buffer, ONE barrier per K-step, 2-deep reg prefetch.
__global__ __launch_bounds__(256) void k_gemm(const float* __restrict__ ref,
                                              const ushort* __restrict__ Wb,
                                              const float* __restrict__ eq,
                                              const float* __restrict__ v,
                                              float* __restrict__ part) {
    __shared__ ushort As[2 * BUFO];
    __shared__ ushort Bs[2 * BUFO];

    int tid = threadIdx.x;
    int lane = tid & 63, wid = tid >> 6;
    int wr = wid >> 1, wc = wid & 1;

    // XCD-aware swizzle: the 4 n-tiles of one m-tile land on the same XCD
    int phys = blockIdx.x;
    int xcd = phys & 7, slot = phys >> 3;         // 8 XCDs x 256 slots
    int mt = xcd * 64 + (slot >> 2);              // 512 m-tiles
    int nt = slot & 3;                            // 4 n-tiles
    int m0 = mt * 128, n0 = nt * 128;
    int b = mt >> 4;                              // 16 m-tiles per batch

    f32x4 acc[4][4];
#pragma unroll
    for (int i = 0; i < 4; ++i)
#pragma unroll
        for (int j = 0; j < 4; ++j) acc[i][j] = (f32x4)(0.f);

    int srow = tid >> 1, sks = (tid & 1) * 16;    // row 0..127, 16-elem half
    const float*  asrc = ref + (size_t)(m0 + srow) * NH + sks;
    const ushort* bsrc = Wb + (size_t)(n0 + srow) * NH + sks;
    int awr = srow * LDST + sks;

    int lr = lane & 15, kq = lane >> 4;
    int aoff[4], boff[4];
#pragma unroll
    for (int f = 0; f < 4; ++f) {
        aoff[f] = (wr * 64 + f * 16 + lr) * LDST + kq * 8;
        boff[f] = (wc * 64 + f * 16 + lr) * LDST + kq * 8;
    }

    // ---- prologue: tile 0 -> LDS[0]; tile 1 -> regs ----
    float4 pa0, pa1, pa2, pa3;
    int4 pb0, pb1;
    {
        const float* s = asrc;
        pa0 = *(const float4*)(s);
        pa1 = *(const float4*)(s + 4);
        pa2 = *(const float4*)(s + 8);
        pa3 = *(const float4*)(s + 12);
        const int4* bs = (const int4*)(bsrc);
        pb0 = bs[0];
        pb1 = bs[1];
        union { ushort u[8]; int4 v; } p0, p1;
        p0.u[0] = f2bf(pa0.x); p0.u[1] = f2bf(pa0.y); p0.u[2] = f2bf(pa0.z); p0.u[3] = f2bf(pa0.w);
        p0.u[4] = f2bf(pa1.x); p0.u[5] = f2bf(pa1.y); p0.u[6] = f2bf(pa1.z); p0.u[7] = f2bf(pa1.w);
        p1.u[0] = f2bf(pa2.x); p1.u[1] = f2bf(pa2.y); p1.u[2] = f2bf(pa2.z); p1.u[3] = f2bf(pa2.w);
        p1.u[4] = f2bf(pa3.x); p1.u[5] = f2bf(pa3.y); p1.u[6] = f2bf(pa3.z); p1.u[7] = f2bf(pa3.w);
        *(int4*)&As[awr] = p0.v;
        *(int4*)&As[awr + 8] = p1.v;
        *(int4*)&Bs[awr] = pb0;
        *(int4*)&Bs[awr + 8] = pb1;
        // tile 1 into prefetch regs
        const float* s1 = asrc + 32;
        pa0 = *(const float4*)(s1);
        pa1 = *(const float4*)(s1 + 4);
        pa2 = *(const float4*)(s1 + 8);
        pa3 = *(const float4*)(s1 + 12);
        const int4* bs1 = (const int4*)(bsrc + 32);
        pb0 = bs1[0];
        pb1 = bs1[1];
    }
    __syncthreads();

    // ---- main loop: one barrier per K-step ----
    for (int kt = 0; kt < 16; ++kt) {
        int cur = kt & 1;
        const ushort* Ac = As + cur * BUFO;
        const ushort* Bc = Bs + cur * BUFO;
        ushort* An = (ushort*)As + (cur ^ 1) * BUFO;
        ushort* Bn = (ushort*)Bs + (cur ^ 1) * BUFO;

        // 1) read current fragments
        s16x8 af[4], bf[4];
#pragma unroll
        for (int f = 0; f < 4; ++f) af[f] = *(const s16x8*)&Ac[aoff[f]];
#pragma unroll
        for (int f = 0; f < 4; ++f) bf[f] = *(const s16x8*)&Bc[boff[f]];

        // 2) pack tile kt+1 (in prefetch regs) into the other buffer
        if (kt < 15) {
            union { ushort u[8]; int4 v; } p0, p1;
            p0.u[0] = f2bf(pa0.x); p0.u[1] = f2bf(pa0.y); p0.u[2] = f2bf(pa0.z); p0.u[3] = f2bf(pa0.w);
            p0.u[4] = f2bf(pa1.x); p0.u[5] = f2bf(pa1.y); p0.u[6] = f2bf(pa1.z); p0.u[7] = f2bf(pa1.w);
            p1.u[0] = f2bf(pa2.x); p1.u[1] = f2bf(pa2.y); p1.u[2] = f2bf(pa2.z); p1.u[3] = f2bf(pa2.w);
            p1.u[4] = f2bf(pa3.x); p1.u[5] = f2bf(pa3.y); p1.u[6] = f2bf(pa3.z); p1.u[7] = f2bf(pa3.w);
            *(int4*)&An[awr] = p0.v;
            *(int4*)&An[awr + 8] = p1.v;
            *(int4*)&Bn[awr] = pb0;
            *(int4*)&Bn[awr + 8] = pb1;
        }
        // 3) issue global loads for tile kt+2 (consumed next iteration)
        if (kt < 14) {
            const float* s = asrc + (kt + 2) * 32;
            pa0 = *(const float4*)(s);
            pa1 = *(const float4*)(s + 4);
            pa2 = *(const float4*)(s + 8);
            pa3 = *(const float4*)(s + 12);
            const int4* bs = (const int4*)(bsrc + (kt + 2) * 32);
            pb0 = bs[0];
            pb1 = bs[1];
        }
        // 4) MFMA on current fragments
#pragma unroll
        for (int fr = 0; fr < 4; ++fr)
#pragma unroll
            for (int fc = 0; fc < 4; ++fc)
                acc[fr][fc] = __builtin_amdgcn_mfma_f32_16x16x32_bf16(
                    af[fr], bf[fc], acc[fr][fc], 0, 0, 0);
        // 5) single barrier: next-buffer writes done, current-buffer reads done
        __syncthreads();
    }

    // epilogue: partial score = sum_{o in tile} v[o]*tanh(e + eq[b][o])
    const float* eqb = eq + b * NH;
    float vv[4], ee[4];
#pragma unroll
    for (int fc = 0; fc < 4; ++fc) {
        int c = n0 + wc * 64 + fc * 16 + lr;
        vv[fc] = v[c];
        ee[fc] = eqb[c];
    }
#pragma unroll
    for (int fr = 0; fr < 4; ++fr) {
#pragma unroll
        for (int reg = 0; reg < 4; ++reg) {
            float s = 0.f;
#pragma unroll
            for (int fc = 0; fc < 4; ++fc) {
                float x = acc[fr][fc][reg] + ee[fc];
                float t = 1.f - 2.f / (__expf(2.f * x) + 1.f);  // tanh
                s += vv[fc] * t;
            }
            s += __shfl_xor(s, 1);
            s += __shfl_xor(s, 2);
            s += __shfl_xor(s, 4);
            s += __shfl_xor(s, 8);
            if (lr == 0) {
                int row = wr * 64 + fr * 16 + kq * 4 + reg;
                part[(size_t)nt * NM + m0 + row] = s;
            }
        }
    }
}

// ---- per-batch: combine partials, mask, write scores, softmax -> attn ----
__global__ __launch_bounds__(256) void k_softmax(const float* __restrict__ part,
                                                 const int* __restrict__ mask,
                                                 float* __restrict__ out_sc,
                                                 float* __restrict__ attn) {
    int b = blockIdx.x;
    int tid = threadIdx.x;
    int lane = tid & 63, wid = tid >> 6;
    __shared__ float red[4];
    float sc[8];
    float mx = -3.4e38f;
#pragma unroll
    for (int i = 0; i < 8; ++i) {
        int m = b * NL + i * 256 + tid;
        float s = (part[m] + part[NM + m] + part[2 * NM + m] + part[3 * NM + m]) * SCALE;
        if (mask[m] != 0) s = -1e9f;
        out_sc[m] = s;
        sc[i] = s;
        mx = fmaxf(mx, s);
    }
#pragma unroll
    for (int o = 32; o >= 1; o >>= 1) mx = fmaxf(mx, __shfl_xor(mx, o));
    if (lane == 0) red[wid] = mx;
    __syncthreads();
    mx = fmaxf(fmaxf(red[0], red[1]), fmaxf(red[2], red[3]));
    __syncthreads();
    float ls = 0.f;
#pragma unroll
    for (int i = 0; i < 8; ++i) {
        float e = __expf(sc[i] - mx);
        sc[i] = e;
        ls += e;
    }
#pragma unroll
    for (int o = 32; o >= 1; o >>= 1) ls += __shfl_xor(ls, o);
    if (lane == 0) red[wid] = ls;
    __syncthreads();
    float inv = 1.f / (red[0] + red[1] + red[2] + red[3]);
#pragma unroll
    for (int i = 0; i < 8; ++i) attn[b * NL + i * 256 + tid] = sc[i] * inv;
}

// ---- glimpse partials: grid (16 splits, 32 batches) ----
__global__ __launch_bounds__(256) void k_glp(const float* __restrict__ ref,
                                             const float* __restrict__ attn,
                                             float* __restrict__ glp) {
    int sp = blockIdx.x, b = blockIdx.y;
    int tid = threadIdx.x;
    const float* attb = attn + b * NL + sp * 128;
    float2 acc = make_float2(0.f, 0.f);
#pragma unroll 4
    for (int l = 0; l < 128; ++l) {
        float a = attb[l];
        const float2* row = (const float2*)(ref + (size_t)(b * NL + sp * 128 + l) * NH);
        float2 r = row[tid];
        acc.x += a * r.x;
        acc.y += a * r.y;
    }
    ((float2*)(glp + (size_t)(sp * NB + b) * NH))[tid] = acc;
}

// ---- reduce glimpse partials ----
__global__ __launch_bounds__(256) void k_gred(const float* __restrict__ glp,
                                              float* __restrict__ out_gl) {
    int idx = blockIdx.x * 256 + threadIdx.x;   // 16384 = B*H
    float s = 0.f;
#pragma unroll
    for (int sp = 0; sp < 16; ++sp) s += glp[sp * (NB * NH) + idx];
    out_gl[idx] = s;
}

extern "C" void kernel_launch(void* const* d_in, const int* in_sizes, int n_in,
                              void* d_out, int out_size, void* d_ws, size_t ws_size,
                              hipStream_t stream) {
    const float* query = (const float*)d_in[0];
    const float* ref   = (const float*)d_in[1];
    const int*   mask  = (const int*)d_in[2];
    const float* W_ref = (const float*)d_in[3];
    const float* W_q   = (const float*)d_in[4];
    const float* v     = (const float*)d_in[5];

    float* out_gl = (float*)d_out;              // 32*512
    float* out_sc = out_gl + NB * NH;           // 32*2048

    char* w = (char*)d_ws;
    ushort* wW  = (ushort*)w;                   // 512*512*2  = 524288 B
    float* eq   = (float*)(w + 524288);         // 32*512*4   = 65536 B
    float* part = (float*)(w + 589824);         // 4*65536*4  = 1048576 B
    float* attn = (float*)(w + 1638400);        // 65536*4    = 262144 B
    float* glp  = (float*)(w + 1900544);        // 16*32*512*4= 1048576 B

    k_convW<<<128, 256, 0, stream>>>(W_ref, wW);
    k_eq<<<NB, 512, 0, stream>>>(query, W_q, eq);
    k_gemm<<<2048, 256, 0, stream>>>(ref, wW, eq, v, part);
    k_softmax<<<NB, 256, 0, stream>>>(part, mask, out_sc, attn);
    k_glp<<<dim3(16, NB), 256, 0, stream>>>(ref, attn, glp);
    k_gred<<<64, 256, 0, stream>>>(glp, out_gl);
}

// Round 4
// 143.008 us; speedup vs baseline: 1.6939x; 1.6939x over previous
//
#include <hip/hip_runtime.h>
#include <hip/hip_bf16.h>
#include <cstdint>

typedef __attribute__((ext_vector_type(4))) float f32x4;
typedef __attribute__((ext_vector_type(8))) short s16x8;

#define NB   32
#define NL   2048
#define NH   512
#define NM   (NB * NL)          // 65536 rows
#define SCALE 0.04419417382415922f  // 1/sqrt(512)
#define LDST 36                 // padded LDS row stride (ushorts): 18 dwords, gcd(18,32)=2 -> uniform banks
#define BUFO (128 * LDST)       // ushorts per LDS buffer

__device__ __forceinline__ ushort f2bf(float f) {
    __hip_bfloat16 b = __float2bfloat16(f);   // pairs fuse into v_cvt_pk_bf16_f32
    return *reinterpret_cast<ushort*>(&b);
}

// ---- convert W_ref (512x512 f32) to bf16 ----
__global__ __launch_bounds__(256) void k_convW(const float* __restrict__ W,
                                               ushort* __restrict__ Wb) {
    int i = blockIdx.x * 256 + threadIdx.x;        // 32768 threads, 8 f32 each
    const float4* s = (const float4*)W;
    float4 a = s[2 * i], c = s[2 * i + 1];
    union { ushort u[8]; int4 v; } p;
    p.u[0] = f2bf(a.x); p.u[1] = f2bf(a.y); p.u[2] = f2bf(a.z); p.u[3] = f2bf(a.w);
    p.u[4] = f2bf(c.x); p.u[5] = f2bf(c.y); p.u[6] = f2bf(c.z); p.u[7] = f2bf(c.w);
    ((int4*)Wb)[i] = p.v;
}

// ---- eq[b][o] = dot(query[b,:], W_q[o,:]) ----
__global__ __launch_bounds__(512) void k_eq(const float* __restrict__ query,
                                            const float* __restrict__ Wq,
                                            float* __restrict__ eq) {
    int b = blockIdx.x;
    int o = threadIdx.x;
    __shared__ float q[NH];
    q[o] = query[b * NH + o];
    __syncthreads();
    const float4* w = (const float4*)(Wq + (size_t)o * NH);
    float acc = 0.f;
#pragma unroll 4
    for (int i = 0; i < NH / 4; ++i) {
        float4 x = w[i];
        acc += q[4 * i] * x.x + q[4 * i + 1] * x.y + q[4 * i + 2] * x.z + q[4 * i + 3] * x.w;
    }
    eq[b * NH + o] = acc;
}

// ---- fused GEMM (ref @ W_ref^T) + tanh + v-dot partial ----
// grid 2048 x 256 thr. Tile 128x128, K-step 32, 4 waves (2x2), 4x4 frags/wave.
// 2-phase, ONE barrier/kt, T14 order (issue-early, write-late), static dbuf via x2 unroll.
__global__ __launch_bounds__(256) void k_gemm(const float* __restrict__ ref,
                                              const ushort* __restrict__ Wb,
                                              const float* __restrict__ eq,
                                              const float* __restrict__ v,
                                              float* __restrict__ part) {
    __shared__ ushort As[2 * BUFO];
    __shared__ ushort Bs[2 * BUFO];

    int tid = threadIdx.x;
    int lane = tid & 63, wid = tid >> 6;
    int wr = wid >> 1, wc = wid & 1;

    // XCD-aware swizzle: the 4 n-tiles of one m-tile land on the same XCD
    int phys = blockIdx.x;
    int xcd = phys & 7, slot = phys >> 3;         // 8 XCDs x 256 slots
    int mt = xcd * 64 + (slot >> 2);              // 512 m-tiles
    int nt = slot & 3;                            // 4 n-tiles
    int m0 = mt * 128, n0 = nt * 128;
    int b = mt >> 4;                              // 16 m-tiles per batch

    f32x4 acc[4][4];
#pragma unroll
    for (int i = 0; i < 4; ++i)
#pragma unroll
        for (int j = 0; j < 4; ++j) acc[i][j] = (f32x4)(0.f);

    int srow = tid >> 1, sks = (tid & 1) * 16;    // row 0..127, 16-elem half
    const float*  asrc = ref + (size_t)(m0 + srow) * NH + sks;
    const ushort* bsrc = Wb + (size_t)(n0 + srow) * NH + sks;
    int awr = srow * LDST + sks;

    int lr = lane & 15, kq = lane >> 4;
    int aoff[4], boff[4];
#pragma unroll
    for (int f = 0; f < 4; ++f) {
        aoff[f] = (wr * 64 + f * 16 + lr) * LDST + kq * 8;
        boff[f] = (wc * 64 + f * 16 + lr) * LDST + kq * 8;
    }

#define LOAD_TILE(kt)                                          \
    {   const float* s_ = asrc + (kt) * 32;                    \
        pa0 = *(const float4*)(s_);                            \
        pa1 = *(const float4*)(s_ + 4);                        \
        pa2 = *(const float4*)(s_ + 8);                        \
        pa3 = *(const float4*)(s_ + 12);                       \
        const int4* bs_ = (const int4*)(bsrc + (kt) * 32);     \
        pb0 = bs_[0];                                          \
        pb1 = bs_[1]; }

#define WRITE_TILE(AB, BB)                                                                         \
    {   union { ushort u[8]; int4 v; } p0, p1;                                                     \
        p0.u[0] = f2bf(pa0.x); p0.u[1] = f2bf(pa0.y); p0.u[2] = f2bf(pa0.z); p0.u[3] = f2bf(pa0.w);\
        p0.u[4] = f2bf(pa1.x); p0.u[5] = f2bf(pa1.y); p0.u[6] = f2bf(pa1.z); p0.u[7] = f2bf(pa1.w);\
        p1.u[0] = f2bf(pa2.x); p1.u[1] = f2bf(pa2.y); p1.u[2] = f2bf(pa2.z); p1.u[3] = f2bf(pa2.w);\
        p1.u[4] = f2bf(pa3.x); p1.u[5] = f2bf(pa3.y); p1.u[6] = f2bf(pa3.z); p1.u[7] = f2bf(pa3.w);\
        *(int4*)&(AB)[awr] = p0.v;                                                                 \
        *(int4*)&(AB)[awr + 8] = p1.v;                                                             \
        *(int4*)&(BB)[awr] = pb0;                                                                  \
        *(int4*)&(BB)[awr + 8] = pb1; }

#define READ_FRAGS(AB, BB)                                      \
    _Pragma("unroll")                                           \
    for (int f = 0; f < 4; ++f) af[f] = *(const s16x8*)&(AB)[aoff[f]]; \
    _Pragma("unroll")                                           \
    for (int f = 0; f < 4; ++f) bf[f] = *(const s16x8*)&(BB)[boff[f]];

#define DO_MFMA()                                               \
    _Pragma("unroll")                                           \
    for (int fr = 0; fr < 4; ++fr)                              \
        _Pragma("unroll")                                       \
        for (int fc = 0; fc < 4; ++fc)                          \
            acc[fr][fc] = __builtin_amdgcn_mfma_f32_16x16x32_bf16(af[fr], bf[fc], acc[fr][fc], 0, 0, 0);

    float4 pa0, pa1, pa2, pa3;
    int4 pb0, pb1;

    // ---- prologue: tile 0 -> buf0 ----
    LOAD_TILE(0)
    WRITE_TILE(As, Bs)
    __syncthreads();

    for (int kt2 = 0; kt2 < 8; ++kt2) {
        s16x8 af[4], bf[4];
        // ===== half 1: compute tile 2*kt2 from buf0; stage tile 2*kt2+1 -> buf1 =====
        LOAD_TILE(2 * kt2 + 1)                       // issue early
        READ_FRAGS(As, Bs)                           // buf0 (offset 0, compile-time)
        DO_MFMA()
        __builtin_amdgcn_sched_barrier(0);           // keep write phase after MFMA
        WRITE_TILE(As + BUFO, Bs + BUFO)             // buf1
        __syncthreads();

        // ===== half 2: compute tile 2*kt2+1 from buf1; stage tile 2*kt2+2 -> buf0 =====
        if (kt2 < 7) {
            LOAD_TILE(2 * kt2 + 2)
            READ_FRAGS(As + BUFO, Bs + BUFO)
            DO_MFMA()
            __builtin_amdgcn_sched_barrier(0);
            WRITE_TILE(As, Bs)
            __syncthreads();
        } else {
            READ_FRAGS(As + BUFO, Bs + BUFO)
            DO_MFMA()
        }
    }

    // epilogue: partial score = sum_{o in tile} v[o]*tanh(e + eq[b][o])
    const float* eqb = eq + b * NH;
    float vv[4], ee[4];
#pragma unroll
    for (int fc = 0; fc < 4; ++fc) {
        int c = n0 + wc * 64 + fc * 16 + lr;
        vv[fc] = v[c];
        ee[fc] = eqb[c];
    }
#pragma unroll
    for (int fr = 0; fr < 4; ++fr) {
#pragma unroll
        for (int reg = 0; reg < 4; ++reg) {
            float s = 0.f;
#pragma unroll
            for (int fc = 0; fc < 4; ++fc) {
                float x = acc[fr][fc][reg] + ee[fc];
                float t = 1.f - 2.f / (__expf(2.f * x) + 1.f);  // tanh
                s += vv[fc] * t;
            }
            s += __shfl_xor(s, 1);
            s += __shfl_xor(s, 2);
            s += __shfl_xor(s, 4);
            s += __shfl_xor(s, 8);
            if (lr == 0) {
                int row = wr * 64 + fr * 16 + kq * 4 + reg;
                part[(size_t)nt * NM + m0 + row] = s;
            }
        }
    }
}

// ---- per-batch: combine partials, mask, write scores, softmax -> attn ----
__global__ __launch_bounds__(256) void k_softmax(const float* __restrict__ part,
                                                 const int* __restrict__ mask,
                                                 float* __restrict__ out_sc,
                                                 float* __restrict__ attn) {
    int b = blockIdx.x;
    int tid = threadIdx.x;
    int lane = tid & 63, wid = tid >> 6;
    __shared__ float red[4];
    float sc[8];
    float mx = -3.4e38f;
#pragma unroll
    for (int i = 0; i < 8; ++i) {
        int m = b * NL + i * 256 + tid;
        float s = (part[m] + part[NM + m] + part[2 * NM + m] + part[3 * NM + m]) * SCALE;
        if (mask[m] != 0) s = -1e9f;
        out_sc[m] = s;
        sc[i] = s;
        mx = fmaxf(mx, s);
    }
#pragma unroll
    for (int o = 32; o >= 1; o >>= 1) mx = fmaxf(mx, __shfl_xor(mx, o));
    if (lane == 0) red[wid] = mx;
    __syncthreads();
    mx = fmaxf(fmaxf(red[0], red[1]), fmaxf(red[2], red[3]));
    __syncthreads();
    float ls = 0.f;
#pragma unroll
    for (int i = 0; i < 8; ++i) {
        float e = __expf(sc[i] - mx);
        sc[i] = e;
        ls += e;
    }
#pragma unroll
    for (int o = 32; o >= 1; o >>= 1) ls += __shfl_xor(ls, o);
    if (lane == 0) red[wid] = ls;
    __syncthreads();
    float inv = 1.f / (red[0] + red[1] + red[2] + red[3]);
#pragma unroll
    for (int i = 0; i < 8; ++i) attn[b * NL + i * 256 + tid] = sc[i] * inv;
}

// ---- glimpse partials: grid (16 splits, 32 batches) ----
__global__ __launch_bounds__(256) void k_glp(const float* __restrict__ ref,
                                             const float* __restrict__ attn,
                                             float* __restrict__ glp) {
    int sp = blockIdx.x, b = blockIdx.y;
    int tid = threadIdx.x;
    const float* attb = attn + b * NL + sp * 128;
    float2 acc = make_float2(0.f, 0.f);
#pragma unroll 4
    for (int l = 0; l < 128; ++l) {
        float a = attb[l];
        const float2* row = (const float2*)(ref + (size_t)(b * NL + sp * 128 + l) * NH);
        float2 r = row[tid];
        acc.x += a * r.x;
        acc.y += a * r.y;
    }
    ((float2*)(glp + (size_t)(sp * NB + b) * NH))[tid] = acc;
}

// ---- reduce glimpse partials ----
__global__ __launch_bounds__(256) void k_gred(const float* __restrict__ glp,
                                              float* __restrict__ out_gl) {
    int idx = blockIdx.x * 256 + threadIdx.x;   // 16384 = B*H
    float s = 0.f;
#pragma unroll
    for (int sp = 0; sp < 16; ++sp) s += glp[sp * (NB * NH) + idx];
    out_gl[idx] = s;
}

extern "C" void kernel_launch(void* const* d_in, const int* in_sizes, int n_in,
                              void* d_out, int out_size, void* d_ws, size_t ws_size,
                              hipStream_t stream) {
    const float* query = (const float*)d_in[0];
    const float* ref   = (const float*)d_in[1];
    const int*   mask  = (const int*)d_in[2];
    const float* W_ref = (const float*)d_in[3];
    const float* W_q   = (const float*)d_in[4];
    const float* v     = (const float*)d_in[5];

    float* out_gl = (float*)d_out;              // 32*512
    float* out_sc = out_gl + NB * NH;           // 32*2048

    char* w = (char*)d_ws;
    ushort* wW  = (ushort*)w;                   // 512*512*2  = 524288 B
    float* eq   = (float*)(w + 524288);         // 32*512*4   = 65536 B
    float* part = (float*)(w + 589824);         // 4*65536*4  = 1048576 B
    float* attn = (float*)(w + 1638400);        // 65536*4    = 262144 B
    float* glp  = (float*)(w + 1900544);        // 16*32*512*4= 1048576 B

    k_convW<<<128, 256, 0, stream>>>(W_ref, wW);
    k_eq<<<NB, 512, 0, stream>>>(query, W_q, eq);
    k_gemm<<<2048, 256, 0, stream>>>(ref, wW, eq, v, part);
    k_softmax<<<NB, 256, 0, stream>>>(part, mask, out_sc, attn);
    k_glp<<<dim3(16, NB), 256, 0, stream>>>(ref, attn, glp);
    k_gred<<<64, 256, 0, stream>>>(glp, out_gl);
}